// Round 1
// baseline (163.517 us; speedup 1.0000x reference)
//
#include <hip/hip_runtime.h>
#include <math.h>

// Additive (Bahdanau) attention, fully fused.
// Sizes fixed by the reference: N=4, NQ=256, NV=512, NE=256, fp32 throughout.
#define N_B   4
#define NQ_   256
#define NV_   512
#define NE_   256
#define QT_   4      // q-rows per block (context/memory reuse factor)
#define NW_   8      // waves per block
#define BLK_  512    // threads per block

__device__ __forceinline__ float wave_reduce_sum(float v) {
#pragma unroll
    for (int m = 32; m > 0; m >>= 1) v += __shfl_xor(v, m, 64);
    return v;
}

__global__ __launch_bounds__(BLK_) void attn_fused(
    const float* __restrict__ Q,     // [N][NQ][NE]
    const float* __restrict__ C,     // [N][NV][NE]
    const float* __restrict__ M,     // [N][NV][NE]
    const float* __restrict__ WL,    // [NE]
    const float* __restrict__ TEMP,  // scalar
    const float* __restrict__ WR,    // [NE][NE] (torch: out = h @ WR^T + BR)
    const float* __restrict__ BR,    // [NE]
    float* __restrict__ OUT)         // [N][NQ][NE]
{
    const int n   = blockIdx.y;
    const int q0  = blockIdx.x * QT_;
    const int tid = threadIdx.x;
    const int wv  = tid >> 6;   // wave id 0..7
    const int ln  = tid & 63;   // lane

    __shared__ __align__(16) float s_prob[QT_][NV_];        // 8 KB: S-values -> probs
    __shared__ __align__(16) float s_part[NW_][QT_][NE_];   // 32 KB: partial heads
    __shared__ __align__(16) float s_heads[QT_][NE_];       // 4 KB

    // ---- preload per-lane fragments: doubled q rows + w_logit ----
    float4 q2[QT_];
    {
        const float4* Q4 = (const float4*)(Q + ((size_t)n * NQ_ + q0) * NE_);
#pragma unroll
        for (int t = 0; t < QT_; ++t) {
            float4 v = Q4[t * (NE_ / 4) + ln];
            q2[t] = make_float4(v.x + v.x, v.y + v.y, v.z + v.z, v.w + v.w);
        }
    }
    const float4 wl = ((const float4*)WL)[ln];

    // ---- phase 1: S[q][v] = sum_e w[e] * sigmoid-ish term ----
    // tanh(x) = 1 - 2*r, r = rcp(1 + exp(2x)).  logit = sum w*tanh = (sum w) - 2*sum w*r.
    // (sum w) is constant over v -> softmax-invariant -> only S = sum w*r is needed.
    const float4* C4 = (const float4*)(C + (size_t)n * NV_ * NE_);
    for (int v = wv; v < NV_; v += NW_) {
        float4 c = C4[v * (NE_ / 4) + ln];
        const float c2x = c.x + c.x, c2y = c.y + c.y;
        const float c2z = c.z + c.z, c2w = c.w + c.w;
        float acc[QT_];
#pragma unroll
        for (int t = 0; t < QT_; ++t) {
            float a;
            a = wl.x * __builtin_amdgcn_rcpf(1.0f + __expf(q2[t].x + c2x));
            a = fmaf(wl.y, __builtin_amdgcn_rcpf(1.0f + __expf(q2[t].y + c2y)), a);
            a = fmaf(wl.z, __builtin_amdgcn_rcpf(1.0f + __expf(q2[t].z + c2z)), a);
            a = fmaf(wl.w, __builtin_amdgcn_rcpf(1.0f + __expf(q2[t].w + c2w)), a);
            acc[t] = a;
        }
#pragma unroll
        for (int t = 0; t < QT_; ++t) acc[t] = wave_reduce_sum(acc[t]);
        if (ln == 0) {
#pragma unroll
            for (int t = 0; t < QT_; ++t) s_prob[t][v] = acc[t];
        }
    }
    __syncthreads();

    // ---- phase 2: softmax over v for each q (logit = -2*S/temp; b_logit invariant) ----
    if (wv < QT_) {
        const int q = wv;
        const float scale = -2.0f / TEMP[0];
        float l[NV_ / 64];
        float mx = -1e30f;
#pragma unroll
        for (int k = 0; k < NV_ / 64; ++k) {
            l[k] = s_prob[q][ln + 64 * k] * scale;
            mx = fmaxf(mx, l[k]);
        }
#pragma unroll
        for (int m = 32; m > 0; m >>= 1) mx = fmaxf(mx, __shfl_xor(mx, m, 64));
        float sum = 0.0f;
#pragma unroll
        for (int k = 0; k < NV_ / 64; ++k) {
            l[k] = __expf(l[k] - mx);
            sum += l[k];
        }
        sum = wave_reduce_sum(sum);
        const float inv = 1.0f / sum;
#pragma unroll
        for (int k = 0; k < NV_ / 64; ++k) s_prob[q][ln + 64 * k] = l[k] * inv;
    }
    __syncthreads();

    // ---- phase 3: heads[q][e] = sum_v probs[q][v] * M[v][e]; waves partition v ----
    const float4* M4 = (const float4*)(M + (size_t)n * NV_ * NE_);
    float4 h[QT_];
#pragma unroll
    for (int t = 0; t < QT_; ++t) h[t] = make_float4(0.f, 0.f, 0.f, 0.f);
    const int v0 = wv * (NV_ / NW_);
    for (int v = v0; v < v0 + NV_ / NW_; ++v) {
        float4 m = M4[v * (NE_ / 4) + ln];
#pragma unroll
        for (int t = 0; t < QT_; ++t) {
            const float p = s_prob[t][v];
            h[t].x = fmaf(p, m.x, h[t].x);
            h[t].y = fmaf(p, m.y, h[t].y);
            h[t].z = fmaf(p, m.z, h[t].z);
            h[t].w = fmaf(p, m.w, h[t].w);
        }
    }
#pragma unroll
    for (int t = 0; t < QT_; ++t) ((float4*)s_part[wv][t])[ln] = h[t];
    __syncthreads();

    // reduce the 8 wave-partials, apply leaky_relu(0.01)
    for (int i = tid; i < QT_ * NE_; i += BLK_) {
        const int t = i >> 8, e = i & (NE_ - 1);
        float s = 0.0f;
#pragma unroll
        for (int w = 0; w < NW_; ++w) s += s_part[w][t][e];
        s_heads[t][e] = (s > 0.0f) ? s : 0.01f * s;
    }
    __syncthreads();

    // ---- phase 4: out[q][e'] = heads[q][:] . WR[e'][:] + BR[e'] ----
    float4 hh[QT_];
#pragma unroll
    for (int t = 0; t < QT_; ++t) hh[t] = ((const float4*)s_heads[t])[ln];
    const float4* W4 = (const float4*)WR;
    float* outp = OUT + ((size_t)n * NQ_ + q0) * NE_;
    for (int r = 0; r < NE_ / NW_; ++r) {
        const int ep = wv * (NE_ / NW_) + r;
        const float4 w = W4[ep * (NE_ / 4) + ln];
        float s[QT_];
#pragma unroll
        for (int t = 0; t < QT_; ++t) {
            float d = hh[t].x * w.x;
            d = fmaf(hh[t].y, w.y, d);
            d = fmaf(hh[t].z, w.z, d);
            d = fmaf(hh[t].w, w.w, d);
            s[t] = wave_reduce_sum(d);
        }
        if (ln == 0) {
            const float b = BR[ep];
#pragma unroll
            for (int t = 0; t < QT_; ++t) outp[t * NE_ + ep] = s[t] + b;
        }
    }
}

extern "C" void kernel_launch(void* const* d_in, const int* in_sizes, int n_in,
                              void* d_out, int out_size, void* d_ws, size_t ws_size,
                              hipStream_t stream) {
    const float* Q  = (const float*)d_in[0];
    const float* C  = (const float*)d_in[1];
    const float* M  = (const float*)d_in[2];
    const float* WL = (const float*)d_in[3];
    // d_in[4] = b_logit: constant over v -> softmax-invariant -> unused.
    const float* T  = (const float*)d_in[5];
    const float* WR = (const float*)d_in[6];
    const float* BR = (const float*)d_in[7];
    float* OUT = (float*)d_out;

    dim3 grid(NQ_ / QT_, N_B);
    attn_fused<<<grid, BLK_, 0, stream>>>(Q, C, M, WL, T, WR, BR, OUT);
}

// Round 2
// 119.231 us; speedup vs baseline: 1.3714x; 1.3714x over previous
//
#include <hip/hip_runtime.h>
#include <math.h>

// Additive (Bahdanau) attention, fused, reduce-free inner loops.
// N=4, NQ=256, NV=512, NE=256, fp32.
#define N_B   4
#define NQ_   256
#define NV_   512
#define NE_   256
#define QT_   2      // q-rows per block
#define NW_   8      // waves per block
#define BLK_  512

// 2*log2(e): pre-scale q,c so sigma(-2x) = rcp(1 + exp2(qs+cs))
#define QSCALE 2.8853900817779268f

__device__ __forceinline__ float wave_reduce_sum(float v) {
#pragma unroll
    for (int m = 32; m > 0; m >>= 1) v += __shfl_xor(v, m, 64);
    return v;
}

// ---- prep: C[n][v][e] -> CT[n][e][v], scaled by QSCALE ----
__global__ __launch_bounds__(256) void transpose_C(const float* __restrict__ C,
                                                   float* __restrict__ CT) {
    __shared__ float tile[64][65];
    const int n = blockIdx.z, v0 = blockIdx.x * 64, e0 = blockIdx.y * 64;
    const int col = threadIdx.x & 63, row4 = threadIdx.x >> 6;
    const float* src = C + ((size_t)n * NV_ + v0) * NE_ + e0;
#pragma unroll
    for (int r = 0; r < 16; ++r) {
        const int vl = row4 + r * 4;
        tile[vl][col] = src[(size_t)vl * NE_ + col] * QSCALE;
    }
    __syncthreads();
    float* dst = CT + ((size_t)n * NE_ + e0) * NV_ + v0;
#pragma unroll
    for (int r = 0; r < 16; ++r) {
        const int el = row4 + r * 4;
        dst[(size_t)el * NV_ + col] = tile[col][el];
    }
}

// ---- prep: WR[e'][e] -> WRT[e][e'] ----
__global__ __launch_bounds__(256) void transpose_W(const float* __restrict__ W,
                                                   float* __restrict__ WT) {
    __shared__ float tile[64][65];
    const int r0 = blockIdx.x * 64, c0 = blockIdx.y * 64;
    const int col = threadIdx.x & 63, row4 = threadIdx.x >> 6;
    const float* src = W + (size_t)r0 * NE_ + c0;
#pragma unroll
    for (int r = 0; r < 16; ++r) {
        const int rl = row4 + r * 4;
        tile[rl][col] = src[(size_t)rl * NE_ + col];
    }
    __syncthreads();
    float* dst = WT + (size_t)c0 * NE_ + r0;
#pragma unroll
    for (int r = 0; r < 16; ++r) {
        const int cl = row4 + r * 4;
        dst[(size_t)cl * NE_ + col] = tile[col][cl];
    }
}

__global__ __launch_bounds__(BLK_) void attn_main(
    const float* __restrict__ Q,     // [N][NQ][NE]
    const float* __restrict__ CT,    // [N][NE][NV]  (pre-scaled)
    const float* __restrict__ M,     // [N][NV][NE]
    const float* __restrict__ WL,    // [NE]
    const float* __restrict__ TEMP,  // scalar
    const float* __restrict__ WRT,   // [NE][NE] = WR^T
    const float* __restrict__ BR,    // [NE]
    float* __restrict__ OUT)         // [N][NQ][NE]
{
    const int n   = blockIdx.y;
    const int q0  = blockIdx.x * QT_;
    const int tid = threadIdx.x;
    const int wv  = tid >> 6;
    const int ln  = tid & 63;

    __shared__ __align__(16) float4 s_qw[NE_];              // 4 KB {q0s,q1s,w,0}
    __shared__ __align__(16) float  s_prob[QT_][NV_];       // 4 KB
    __shared__ __align__(16) float  s_part[NW_][QT_][NE_];  // 16 KB
    __shared__ __align__(16) float  s_heads[QT_][NE_];      // 2 KB

    if (tid < NE_) {
        const float a = Q[((size_t)n * NQ_ + q0) * NE_ + tid] * QSCALE;
        const float b = Q[((size_t)n * NQ_ + q0 + 1) * NE_ + tid] * QSCALE;
        s_qw[tid] = make_float4(a, b, WL[tid], 0.0f);
    }
    __syncthreads();

    // ---- phase 1: lane-per-v, loop e. S[t][v] = sum_e w[e]*rcp(1+exp2(qs+cs)) ----
    {
        const float* ct = CT + (size_t)n * NE_ * NV_ + wv * 64 + ln;
        float acc0 = 0.0f, acc1 = 0.0f;
#pragma unroll 8
        for (int e = 0; e < NE_; ++e) {
            const float c = ct[(size_t)e * NV_];
            const float4 qw = s_qw[e];
            const float p0 = __builtin_amdgcn_exp2f(c + qw.x);
            const float p1 = __builtin_amdgcn_exp2f(c + qw.y);
            const float r0 = __builtin_amdgcn_rcpf(1.0f + p0);
            const float r1 = __builtin_amdgcn_rcpf(1.0f + p1);
            acc0 = fmaf(qw.z, r0, acc0);
            acc1 = fmaf(qw.z, r1, acc1);
        }
        s_prob[0][wv * 64 + ln] = acc0;
        s_prob[1][wv * 64 + ln] = acc1;
    }
    __syncthreads();

    // ---- phase 2: softmax over v (logit = -2*S/temp; b_logit is shift-invariant) ----
    if (wv < QT_) {
        const int q = wv;
        const float scale = -2.0f / TEMP[0];
        float l[NV_ / 64];
        float mx = -1e30f;
#pragma unroll
        for (int k = 0; k < NV_ / 64; ++k) {
            l[k] = s_prob[q][ln + 64 * k] * scale;
            mx = fmaxf(mx, l[k]);
        }
#pragma unroll
        for (int m = 32; m > 0; m >>= 1) mx = fmaxf(mx, __shfl_xor(mx, m, 64));
        float sum = 0.0f;
#pragma unroll
        for (int k = 0; k < NV_ / 64; ++k) {
            l[k] = __expf(l[k] - mx);
            sum += l[k];
        }
        sum = wave_reduce_sum(sum);
        const float inv = 1.0f / sum;
#pragma unroll
        for (int k = 0; k < NV_ / 64; ++k) s_prob[q][ln + 64 * k] = l[k] * inv;
    }
    __syncthreads();

    // ---- phase 3: heads[t][e] = sum_v p[t][v]*M[v][e]; waves partition v ----
    {
        const float4* M4 = (const float4*)(M + (size_t)n * NV_ * NE_);
        float4 h0 = make_float4(0.f, 0.f, 0.f, 0.f);
        float4 h1 = make_float4(0.f, 0.f, 0.f, 0.f);
        const int v0 = wv * (NV_ / NW_);
#pragma unroll 4
        for (int v = v0; v < v0 + NV_ / NW_; ++v) {
            const float4 m = M4[v * (NE_ / 4) + ln];
            const float p0 = s_prob[0][v];
            const float p1 = s_prob[1][v];
            h0.x = fmaf(p0, m.x, h0.x); h0.y = fmaf(p0, m.y, h0.y);
            h0.z = fmaf(p0, m.z, h0.z); h0.w = fmaf(p0, m.w, h0.w);
            h1.x = fmaf(p1, m.x, h1.x); h1.y = fmaf(p1, m.y, h1.y);
            h1.z = fmaf(p1, m.z, h1.z); h1.w = fmaf(p1, m.w, h1.w);
        }
        ((float4*)s_part[wv][0])[ln] = h0;
        ((float4*)s_part[wv][1])[ln] = h1;
    }
    __syncthreads();

    // reduce 8 wave-partials + leaky_relu
    {
        const int t = tid >> 8, e = tid & (NE_ - 1);  // 512 threads == QT_*NE_
        float s = 0.0f;
#pragma unroll
        for (int w = 0; w < NW_; ++w) s += s_part[w][t][e];
        s_heads[t][e] = (s > 0.0f) ? s : 0.01f * s;
    }
    __syncthreads();

    // ---- phase 4: out[t][e'] = sum_e h[t][e]*WRT[e][e'] + BR[e'] (reduce-free) ----
    {
        const int t  = wv >> 2;                 // 0..1
        const int ep = ((wv & 3) << 6) + ln;    // 0..255
        const float* wrt = WRT + ep;
        float acc = 0.0f;
#pragma unroll 8
        for (int e = 0; e < NE_; ++e)
            acc = fmaf(s_heads[t][e], wrt[(size_t)e * NE_], acc);
        OUT[((size_t)n * NQ_ + q0 + t) * NE_ + ep] = acc + BR[ep];
    }
}

extern "C" void kernel_launch(void* const* d_in, const int* in_sizes, int n_in,
                              void* d_out, int out_size, void* d_ws, size_t ws_size,
                              hipStream_t stream) {
    const float* Q  = (const float*)d_in[0];
    const float* C  = (const float*)d_in[1];
    const float* M  = (const float*)d_in[2];
    const float* WL = (const float*)d_in[3];
    // d_in[4] = b_logit: softmax shift-invariant -> unused.
    const float* T  = (const float*)d_in[5];
    const float* WR = (const float*)d_in[6];
    const float* BR = (const float*)d_in[7];
    float* OUT = (float*)d_out;

    float* CT  = (float*)d_ws;                       // N*NE*NV   = 524288 floats
    float* WRT = CT + (size_t)N_B * NE_ * NV_;       // NE*NE     = 65536 floats
    // total ws need: ~2.25 MB

    dim3 gtc(NV_ / 64, NE_ / 64, N_B);
    transpose_C<<<gtc, 256, 0, stream>>>(C, CT);
    dim3 gtw(NE_ / 64, NE_ / 64);
    transpose_W<<<gtw, 256, 0, stream>>>(WR, WRT);

    dim3 grid(NQ_ / QT_, N_B);
    attn_main<<<grid, BLK_, 0, stream>>>(Q, CT, M, WL, T, WRT, BR, OUT);
}